// Round 8
// baseline (154.830 us; speedup 1.0000x reference)
//
#include <hip/hip_runtime.h>
#include <hip/hip_bf16.h>
#include <hip/hip_fp16.h>
#include <math.h>

// Decoder: out[e] = sigmoid(relu( W2 . relu( W1 * [x[src]; x[dst]] + b1 ) + b2 ))
// Factorized: Y[n][0:128] = W1_left*x[n] + b1 ; Y[n][128:256] = W1_right*x[n]
//             out[e] = sigmoid(relu( W2 . relu(Yl[src]+Yr[dst]) + b2 ))
// Y stored fp8 e4m3 (25.6 MB).
// R17 == R16 + MEASUREMENT: precompute launched TWICE (idempotent -- reads
// x/W1/b1, writes Y8 deterministically). t_pre = dur(R17) - 132.26.
// Ledger so far (dup-launch algebra, non-kernel budget 108.9us = 2 harness
// fills ~83 + gaps): t_edge 29 -> 22.3 (R15 decode cascade + coalesced ei)
// -> 23.4 (R16 MLP x2 = null -> edge is at L3 gather-BW ceiling ~7.2 TB/s).
// t_pre never measured directly; floor ~12-14us. This round resolves it.
// R16 config kept: EPB 256, 8 edges/8-lane group; precompute = R12 structure.

typedef short    s16x4 __attribute__((ext_vector_type(4)));
typedef short    s16x8 __attribute__((ext_vector_type(8)));
typedef float    f32x2 __attribute__((ext_vector_type(2)));
typedef float    f32x4 __attribute__((ext_vector_type(4)));
typedef unsigned u32x4 __attribute__((ext_vector_type(4)));
typedef _Float16 h16x2 __attribute__((ext_vector_type(2)));

#define D 128

static __device__ inline short f2bf(float f) {
    unsigned u = __builtin_bit_cast(unsigned, f);
    unsigned r = (u + 0x7FFFu + ((u >> 16) & 1u)) >> 16;
    return (short)r;
}

// f32 pair -> packed bf16 dword (RNE), gfx950 (no builtin; T12/m240)
static __device__ inline unsigned pkbf16(float a, float b) {
    unsigned r;
    asm("v_cvt_pk_bf16_f32 %0, %1, %2" : "=v"(r) : "v"(a), "v"(b));
    return r;
}

// async global->LDS 16B; LDS dest = wave-uniform base + lane*16 (m104)
static __device__ inline void stage16(const void* g, void* l) {
    __builtin_amdgcn_global_load_lds(
        (const __attribute__((address_space(1))) void*)g,
        (__attribute__((address_space(3))) void*)l, 16, 0, 0);
}

// ---------- fp8 e4m3 encode (RNE) ----------
static __device__ inline unsigned enc1_sw(float f) {
    f = fminf(fmaxf(f, -448.f), 448.f);
    unsigned short h = __builtin_bit_cast(unsigned short, (_Float16)(f * (1.0f / 256.0f)));
    unsigned s = (h >> 8) & 0x80u;
    unsigned mag = h & 0x7FFFu;
    mag = mag + 0x3Fu + ((mag >> 7) & 1u);        // RNE 10->3 mantissa bits
    return s | ((mag >> 7) & 0x7Fu);
}
static __device__ inline unsigned enc2(float a, float b) {
#if __has_builtin(__builtin_amdgcn_cvt_pk_fp8_f32)
    return ((unsigned)__builtin_amdgcn_cvt_pk_fp8_f32(a, b, 0, false)) & 0xFFFFu;
#else
    return enc1_sw(a) | (enc1_sw(b) << 8);
#endif
}

// ---------- fp8 e4m3 decode paths ----------
#if __has_builtin(__builtin_amdgcn_cvt_pk_f16_fp8)
#define EDGE_PATH 0
#elif __has_builtin(__builtin_amdgcn_cvt_pk_f32_fp8)
#define EDGE_PATH 1
#else
#define EDGE_PATH 2
#endif

#if EDGE_PATH == 0
#define YSC 1.0f
static __device__ inline h16x2 dec2lo(unsigned v) {
    return __builtin_amdgcn_cvt_pk_f16_fp8((short)v);
}
static __device__ inline h16x2 dec2hi(unsigned v) {
    return __builtin_amdgcn_cvt_pk_f16_fp8((short)(v >> 16));
}
#elif EDGE_PATH == 1
static __device__ inline f32x2 d32lo(unsigned v) {
    return __builtin_amdgcn_cvt_pk_f32_fp8((int)v, false);
}
static __device__ inline f32x2 d32hi(unsigned v) {
    return __builtin_amdgcn_cvt_pk_f32_fp8((int)v, true);
}
#else
#define YSC 256.0f
// e4m3 bits<<7 in fp16 = value/256 exactly (incl. subnormals); /256 folded into W2
static __device__ inline h16x2 dec2lo(unsigned v) {
    unsigned p = __builtin_amdgcn_perm(0u, v, 0x0C010C00u);   // [0,b1,0,b0]
    unsigned h = ((p << 8) & 0x80008000u) | ((p << 7) & 0x3F803F80u);
    return __builtin_bit_cast(h16x2, h);
}
static __device__ inline h16x2 dec2hi(unsigned v) {
    unsigned p = __builtin_amdgcn_perm(0u, v, 0x0C030C02u);   // [0,b3,0,b2]
    unsigned h = ((p << 8) & 0x80008000u) | ((p << 7) & 0x3F803F80u);
    return __builtin_bit_cast(h16x2, h);
}
#endif

#if EDGE_PATH != 1
static __device__ inline h16x2 reluh(h16x2 v) {
#if __has_builtin(__builtin_elementwise_max)
    h16x2 z = { (_Float16)0.0f, (_Float16)0.0f };
    return __builtin_elementwise_max(v, z);
#else
    unsigned u = __builtin_bit_cast(unsigned, v);
    unsigned m = ((u >> 15) & 0x00010001u) * 0xFFFFu;
    u &= ~m;
    return __builtin_bit_cast(h16x2, u);
#endif
}
static __device__ inline float dot2acc(h16x2 a, h16x2 b, float c) {
#if __has_builtin(__builtin_amdgcn_fdot2)
    return __builtin_amdgcn_fdot2(a, b, c, false);
#else
    return c + (float)a[0] * (float)b[0] + (float)a[1] * (float)b[1];
#endif
}
#endif

// ---------------- Phase A: Y^T MFMA, gload_lds f32 staging ----------------
#define GRIDA 768   // 3 blocks/CU x 256 CUs (launch_bounds(256,3) guarantees fit)

__global__ __launch_bounds__(256, 3) void precompute_kernel(
    const float* __restrict__ x,    // [N,128]
    const float* __restrict__ W1,   // [128,256]
    const float* __restrict__ b1,   // [128]
    unsigned char* __restrict__ Y8, // [N,256] fp8 e4m3
    int N, int ntiles)
{
    // 2 x 32 rows x 512B, rows XOR-swizzled by ((row&7)<<4) on bytes 4..6
    __shared__ float Xt[2][32 * 128];

    const int tid  = threadIdx.x;
    const int wid  = tid >> 6;                   // wave id = 64-feature col slice
    const int lane = tid & 63;
    const int quad = lane >> 4, l15 = lane & 15;
    const int cs   = wid;

    // ---- build W1 bf16 frags directly (pack kernel merged; once per block)
    // frag (c,j): lane -> W1row[o=cs*64+j*16+l15][k=c*32+quad*8 .. +8]
    s16x8 bf[4][4];   // [k-chunk][col-tile]
    #pragma unroll
    for (int j = 0; j < 4; ++j) {
        #pragma unroll
        for (int c = 0; c < 4; ++c) {
            int o  = cs * 64 + j * 16 + l15;
            int kb = c * 32 + quad * 8;
            const float* wp = W1 + (size_t)(o & 127) * 256 + (o >> 7) * 128 + kb;
            float4 u0 = *(const float4*)wp;
            float4 u1 = *(const float4*)(wp + 4);
            bf[c][j] = (s16x8){ f2bf(u0.x), f2bf(u0.y), f2bf(u0.z), f2bf(u0.w),
                                f2bf(u1.x), f2bf(u1.y), f2bf(u1.z), f2bf(u1.w) };
        }
    }

    // staging geometry: thread covers LDS bytes i*4096 + tid*16, i=0..3
    const int rl   = wid * 2 + (lane >> 5);      // row = i*8 + rl
    const int colb = (lane & 31) * 16;           // in-row byte offset (pre-swizzle)
    const char* xbytes = (const char*)x;

    auto stage_tile = [&](int tt, int bb) {
        char* lb = (char*)&Xt[bb][0] + wid * 1024;   // wave-uniform base
        #pragma unroll
        for (int i = 0; i < 4; ++i) {
            int row = i * 8 + rl;
            int m = tt * 32 + row; if (m >= N) m = N - 1;
            // LDS holds X[row][col ^ sw(row)] at linear (row,col): pre-swizzle src
            stage16(xbytes + (size_t)m * 512 + (colb ^ ((row & 7) << 4)),
                    lb + i * 4096);
        }
    };

    int t = blockIdx.x;
    if (t < ntiles) stage_tile(t, 0);

    const int swz = (l15 & 7) << 4;              // read-side swizzle (r&7 == l15&7)
    int buf = 0;
    while (t < ntiles) {
        const int tn = t + GRIDA;

        // ---- A: drain own staging loads, then barrier (cross-wave visibility)
        asm volatile("s_waitcnt vmcnt(0)" ::: "memory");
        __syncthreads();

        // ---- acc init = bias (folded; left half only), issued early (L2-hot)
        f32x4 acc[2][4];
        #pragma unroll
        for (int j = 0; j < 4; ++j) {
            f32x4 bi = (cs < 2) ? *(const f32x4*)&b1[cs * 64 + j * 16 + quad * 4]
                                : (f32x4){0.f, 0.f, 0.f, 0.f};
            acc[0][j] = bi; acc[1][j] = bi;
        }

        // ---- read x frags from swizzled LDS, convert f32->bf16 in-reg
        // B-operand frag (c,i2): lane -> x[node=i2*16+l15][k=c*32+quad*8 .. +8]
        s16x8 af[2][4];   // [i2][c]
        {
            const char* xb8 = (const char*)&Xt[buf][0];
            #pragma unroll
            for (int i2 = 0; i2 < 2; ++i2) {
                const char* rp = xb8 + (i2 * 16 + l15) * 512;
                #pragma unroll
                for (int c = 0; c < 4; ++c) {
                    int kb = c * 128 + quad * 32;
                    f32x4 lo = *(const f32x4*)(rp + ( kb       ^ swz));
                    f32x4 hi = *(const f32x4*)(rp + ((kb + 16) ^ swz));
                    u32x4 pk;
                    pk[0] = pkbf16(lo[0], lo[1]);
                    pk[1] = pkbf16(lo[2], lo[3]);
                    pk[2] = pkbf16(hi[0], hi[1]);
                    pk[3] = pkbf16(hi[2], hi[3]);
                    af[i2][c] = __builtin_bit_cast(s16x8, pk);
                }
            }
        }

        // ---- B: issue next tile's staging (lands during MFMA + epilogue;
        //      drained at next iteration's vmcnt(0)+barrier)
        if (tn < ntiles) stage_tile(tn, buf ^ 1);

        // ---- MFMA: D = W1frag x xfrag = Y^T (row=feature, col=node)
        #pragma unroll
        for (int c = 0; c < 4; ++c)
            #pragma unroll
            for (int i2 = 0; i2 < 2; ++i2)
                #pragma unroll
                for (int j = 0; j < 4; ++j)
                    acc[i2][j] = __builtin_amdgcn_mfma_f32_16x16x32_bf16(
                        bf[c][j], af[i2][c], acc[i2][j], 0, 0, 0);

        // ---- epilogue: fp8 encode from acc + 4x4 quad transpose -> 16B stores
        // D layout: col=l15 -> node (m0+i2*16+l15), row=quad*4+r -> feature
        // (cs*64 + j*16 + quad*4 + r). dw[j] = one fp8 dword.
        const int m0 = t * 32;
        const bool qb0 = (quad & 1), qb1 = (quad & 2);
        #pragma unroll
        for (int i2 = 0; i2 < 2; ++i2) {
            unsigned dw[4];
            #pragma unroll
            for (int j = 0; j < 4; ++j) {
                f32x4 v = acc[i2][j];
                dw[j] = enc2(v[0], v[1]) | (enc2(v[2], v[3]) << 16);
            }
            // transpose across quads (lanes +-16/+-32): lane q ends with
            // {dw[q] of quad 0..3} = 16 consecutive features at col cs*64+q*16
            unsigned s01 = qb0 ? dw[0] : dw[1];
            unsigned r01 = __shfl_xor(s01, 16);
            unsigned s23 = qb0 ? dw[2] : dw[3];
            unsigned r23 = __shfl_xor(s23, 16);
            unsigned a0 = qb0 ? r01 : dw[0];
            unsigned a1 = qb0 ? dw[1] : r01;
            unsigned a2 = qb0 ? r23 : dw[2];
            unsigned a3 = qb0 ? dw[3] : r23;
            unsigned s02 = qb1 ? a0 : a2;
            unsigned r02 = __shfl_xor(s02, 32);
            unsigned s13 = qb1 ? a1 : a3;
            unsigned r13 = __shfl_xor(s13, 32);
            uint4 ov;
            ov.x = qb1 ? r02 : a0;
            ov.y = qb1 ? r13 : a1;
            ov.z = qb1 ? a2 : r02;
            ov.w = qb1 ? a3 : r13;
            int m = m0 + i2 * 16 + l15;
            if (m < N)
                *(uint4*)(Y8 + (size_t)m * 256 + cs * 64 + quad * 16) = ov;
        }

        buf ^= 1;
        t = tn;
    }
}

// ---------------- Phase B: 8 edges per 8-lane group, fp8 gather ----------------
#define EPB 256   // edges per block (256 threads, 32 groups x 8 edges)

__global__ __launch_bounds__(256, 4) void edge_kernel(
    const unsigned char* __restrict__ Y8,  // [N,256] fp8
    const int*           __restrict__ ei,  // [2,E]
    const float*         __restrict__ W2,  // [128]
    const float*         __restrict__ b2,  // [1]
    float*               __restrict__ out, // [E]
    int E)
{
    __shared__ int eis[2][EPB];                 // [src/dst][edge-in-block]

    const int tid = threadIdx.x;
    const int sub = tid & 7;                    // 8 lanes per edge
    const int grp = tid >> 3;                   // 0..31
    const int e0b = blockIdx.x * EPB;

    // ---- coalesced ei stage: each thread loads one src + one dst index
    {
        int e = e0b + tid;
        eis[0][tid] = (e < E) ? ei[e] : 0;
        eis[1][tid] = (e < E) ? ei[(size_t)E + e] : 0;
    }
    __syncthreads();

    // ---- W2 for this sub-lane's 16 columns
#if EDGE_PATH == 1
    f32x2 w2f[8];
    {
        const float* wp = &W2[sub * 16];
        #pragma unroll
        for (int q = 0; q < 8; ++q)
            w2f[q] = *(const f32x2*)(wp + q * 2);
    }
#else
    h16x2 w2h[8];
    {
        const float* wp = &W2[sub * 16];
        #pragma unroll
        for (int q = 0; q < 8; ++q) {
            float2 f = *(const float2*)(wp + q * 2);
            w2h[q] = (h16x2){ (_Float16)(f.x * YSC), (_Float16)(f.y * YSC) };
        }
    }
#endif

    // ---- issue ALL 16 gather segments before any decode (MLP=16/thread)
    uint4 L[8], R[8];
    #pragma unroll
    for (int k = 0; k < 8; ++k) {
        int ib  = grp + 32 * k;
        int src = eis[0][ib];
        int dst = eis[1][ib];
        L[k] = *(const uint4*)(Y8 + (size_t)src * 256 + sub * 16);
        R[k] = *(const uint4*)(Y8 + (size_t)dst * 256 + 128 + sub * 16);
    }

    float s[8] = { 0.f, 0.f, 0.f, 0.f, 0.f, 0.f, 0.f, 0.f };
    #pragma unroll
    for (int k = 0; k < 8; ++k) {
        const unsigned* a = (const unsigned*)&L[k];
        const unsigned* c = (const unsigned*)&R[k];
        #pragma unroll
        for (int d = 0; d < 4; ++d) {
#if EDGE_PATH == 1
            f32x2 zl = d32lo(a[d]) + d32lo(c[d]);
            f32x2 zh = d32hi(a[d]) + d32hi(c[d]);
            s[k] = fmaf(fmaxf(zl[0], 0.f), w2f[2*d][0], s[k]);
            s[k] = fmaf(fmaxf(zl[1], 0.f), w2f[2*d][1], s[k]);
            s[k] = fmaf(fmaxf(zh[0], 0.f), w2f[2*d + 1][0], s[k]);
            s[k] = fmaf(fmaxf(zh[1], 0.f), w2f[2*d + 1][1], s[k]);
#else
            h16x2 za = reluh(dec2lo(a[d]) + dec2lo(c[d]));
            s[k] = dot2acc(za, w2h[2*d],     s[k]);
            h16x2 zb = reluh(dec2hi(a[d]) + dec2hi(c[d]));
            s[k] = dot2acc(zb, w2h[2*d + 1], s[k]);
#endif
        }
    }

    #pragma unroll
    for (int k = 0; k < 8; ++k) {
        s[k] += __shfl_xor(s[k], 1);
        s[k] += __shfl_xor(s[k], 2);
        s[k] += __shfl_xor(s[k], 4);
    }

    if (sub == 0) {
        float bb = b2[0];
        #pragma unroll
        for (int k = 0; k < 8; ++k) {
            int e = e0b + grp + 32 * k;
            if (e < E) {
                float t = fmaxf(s[k] + bb, 0.f);
                out[e] = 1.0f / (1.0f + expf(-t));
            }
        }
    }
}

// ---------------- fallback (fused edge-wise GEMM, fp32 inputs) ----------------
#define BM   128
#define BK   64
#define LDT  72

__global__ __launch_bounds__(256) void decoder_fallback_kernel(
    const float* __restrict__ x, const int* __restrict__ ei,
    const float* __restrict__ W1, const float* __restrict__ b1,
    const float* __restrict__ W2, const float* __restrict__ b2,
    float* __restrict__ out, int E)
{
    __shared__ int   nid[2][BM];
    __shared__ short At[BM * LDT];
    __shared__ short Bt[D * LDT];
    __shared__ float rowsum[BM][2];

    const int tid = threadIdx.x;
    const int e0  = blockIdx.x * BM;
    if (tid < BM) { int e = e0 + tid; nid[0][tid] = (e < E) ? ei[e] : 0; }
    else { int e = e0 + (tid - BM); nid[1][tid - BM] = (e < E) ? ei[E + e] : 0; }

    const int wid = tid >> 6, lane = tid & 63;
    const int wm = wid >> 1, wn = wid & 1;
    const int quad = lane >> 4, l15 = lane & 15;
    const int srow = tid >> 4, scol = (tid & 15) * 4;
    f32x4 acc[4][4] = {};
    __syncthreads();

    for (int t = 0; t < 4; ++t) {
        const int* ids = nid[t >> 1];
        const int kx = (t & 1) * BK, kw = t * BK;
        #pragma unroll
        for (int p = 0; p < 8; ++p) {
            int row = srow + p * 16;
            float4 v = *(const float4*)&x[(size_t)ids[row] * D + kx + scol];
            s16x4 bv = { f2bf(v.x), f2bf(v.y), f2bf(v.z), f2bf(v.w) };
            *(s16x4*)&At[row * LDT + scol] = bv;
        }
        #pragma unroll
        for (int p = 0; p < 8; ++p) {
            int n = srow + p * 16;
            float4 v = *(const float4*)&W1[n * 256 + kw + scol];
            s16x4 bv = { f2bf(v.x), f2bf(v.y), f2bf(v.z), f2bf(v.w) };
            *(s16x4*)&Bt[n * LDT + scol] = bv;
        }
        __syncthreads();
        #pragma unroll
        for (int c = 0; c < 2; ++c) {
            const int kc = c * 32;
            s16x8 af[4], bfr[4];
            #pragma unroll
            for (int i = 0; i < 4; ++i)
                af[i] = *(const s16x8*)&At[(wm*64 + i*16 + l15) * LDT + kc + quad*8];
            #pragma unroll
            for (int j = 0; j < 4; ++j)
                bfr[j] = *(const s16x8*)&Bt[(wn*64 + j*16 + l15) * LDT + kc + quad*8];
            #pragma unroll
            for (int i = 0; i < 4; ++i)
                #pragma unroll
                for (int j = 0; j < 4; ++j)
                    acc[i][j] = __builtin_amdgcn_mfma_f32_16x16x32_bf16(
                        af[i], bfr[j], acc[i][j], 0, 0, 0);
        }
        __syncthreads();
    }
    float b1v[4], w2v[4];
    #pragma unroll
    for (int j = 0; j < 4; ++j) {
        int col = wn*64 + j*16 + l15;
        b1v[j] = b1[col]; w2v[j] = W2[col];
    }
    float psum[16];
    #pragma unroll
    for (int t = 0; t < 16; ++t) psum[t] = 0.f;
    #pragma unroll
    for (int i = 0; i < 4; ++i)
        #pragma unroll
        for (int j = 0; j < 4; ++j)
            #pragma unroll
            for (int r = 0; r < 4; ++r) {
                float c = fmaxf(acc[i][j][r] + b1v[j], 0.f);
                psum[i*4 + r] += c * w2v[j];
            }
    #pragma unroll
    for (int off = 1; off < 16; off <<= 1)
        #pragma unroll
        for (int t = 0; t < 16; ++t)
            psum[t] += __shfl_xor(psum[t], off);
    if (l15 == 0) {
        #pragma unroll
        for (int i = 0; i < 4; ++i)
            #pragma unroll
            for (int r = 0; r < 4; ++r)
                rowsum[wm*64 + i*16 + quad*4 + r][wn] = psum[i*4 + r];
    }
    __syncthreads();
    if (tid < BM) {
        int e = e0 + tid;
        if (e < E) {
            float s = rowsum[tid][0] + rowsum[tid][1] + b2[0];
            s = fmaxf(s, 0.f);
            out[e] = 1.0f / (1.0f + expf(-s));
        }
    }
}

extern "C" void kernel_launch(void* const* d_in, const int* in_sizes, int n_in,
                              void* d_out, int out_size, void* d_ws, size_t ws_size,
                              hipStream_t stream) {
    const float* x  = (const float*)d_in[0];
    const int*   ei = (const int*)d_in[1];
    const float* W1 = (const float*)d_in[2];
    const float* b1 = (const float*)d_in[3];
    const float* W2 = (const float*)d_in[4];
    const float* b2 = (const float*)d_in[5];
    float* out = (float*)d_out;

    int E = in_sizes[1] / 2;
    int N = in_sizes[0] / D;

    size_t y_bytes = (size_t)N * 256;                    // 25.6 MB fp8
    if (ws_size >= y_bytes) {
        unsigned char* Y8 = (unsigned char*)d_ws;
        int ntiles = (N + 31) / 32;
        int gridA  = (ntiles < GRIDA) ? ntiles : GRIDA;  // 3 blocks/CU, grid-stride
        precompute_kernel<<<gridA, 256, 0, stream>>>(x, W1, b1, Y8, N, ntiles);
        // R17 MEASUREMENT ONLY: duplicate precompute launch (idempotent).
        // t_pre = dur(R17) - 132.26. Remove next round.
        precompute_kernel<<<gridA, 256, 0, stream>>>(x, W1, b1, Y8, N, ntiles);
        int gridB = (E + EPB - 1) / EPB;
        edge_kernel<<<gridB, 256, 0, stream>>>(Y8, ei, W2, b2, out, E);
    } else {
        int nblocks = (E + BM - 1) / BM;
        decoder_fallback_kernel<<<nblocks, 256, 0, stream>>>(
            x, ei, W1, b1, W2, b2, out, E);
    }
}

// Round 9
// 152.187 us; speedup vs baseline: 1.0174x; 1.0174x over previous
//
#include <hip/hip_runtime.h>
#include <hip/hip_bf16.h>
#include <hip/hip_fp16.h>
#include <math.h>

// Decoder: out[e] = sigmoid(relu( W2 . relu( W1 * [x[src]; x[dst]] + b1 ) + b2 ))
// Factorized: Y[n][0:128] = W1_left*x[n] + b1 ; Y[n][128:256] = W1_right*x[n]
//             out[e] = sigmoid(relu( W2 . relu(Yl[src]+Yr[dst]) + b2 ))
// Y stored fp8 e4m3 (25.6 MB).
// LEDGER (dup-launch algebra): fills ~83 (harness, fixed) + pre 22.6 (R17) +
// edge 23.4 (R16) + gaps ~3 = 132.3. Floors: pre ~12, edge ~15.
// R18: two convergent fixes, one theory (missing fp8-cvt builtins + barrier
// serialization):
//  (1) precompute rewritten BARRIER-FREE: each wave loads its x B-frags
//      directly from global (frag chunks are row-contiguous 16B); 4x re-read
//      absorbed by L1/L2. Deletes LDS staging, vmcnt(0) drains, double
//      buffer -- the structure that survived 3 failed pipelining rewrites.
//  (2) fp8 encode/decode via inline asm when builtins absent
//      (v_cvt_pk_fp8_f32 / v_cvt_pk_f32_fp8 exist on gfx950 regardless of
//      header exposure). R15's edge gain (29->22.3) implies the f16 decode
//      builtin WAS missing -> encoder likely missing too -> precompute's
//      epilogue was ~400 sw-VALU/iter, edge may still be VALU-bound (its
//      MLP-null in R16 is consistent with VALU-bound, not only L3-bound).
//  (3) W1-prologue bf16 pack via v_cvt_pk_bf16_f32 asm.
// Edge structure unchanged from R16 (EPB 256, 8 edges/8-lane group).

typedef short    s16x4 __attribute__((ext_vector_type(4)));
typedef short    s16x8 __attribute__((ext_vector_type(8)));
typedef float    f32x2 __attribute__((ext_vector_type(2)));
typedef float    f32x4 __attribute__((ext_vector_type(4)));
typedef unsigned u32x4 __attribute__((ext_vector_type(4)));
typedef _Float16 h16x2 __attribute__((ext_vector_type(2)));

#define D 128

static __device__ inline short f2bf(float f) {
    unsigned u = __builtin_bit_cast(unsigned, f);
    unsigned r = (u + 0x7FFFu + ((u >> 16) & 1u)) >> 16;
    return (short)r;
}

// f32 pair -> packed bf16 dword (RNE), gfx950
static __device__ inline unsigned pkbf16(float a, float b) {
    unsigned r;
    asm("v_cvt_pk_bf16_f32 %0, %1, %2" : "=v"(r) : "v"(a), "v"(b));
    return r;
}

// ---------- fp8 e4m3 encode: HW builtin or direct asm ----------
static __device__ inline unsigned enc2(float a, float b) {
#if __has_builtin(__builtin_amdgcn_cvt_pk_fp8_f32)
    return ((unsigned)__builtin_amdgcn_cvt_pk_fp8_f32(a, b, 0, false)) & 0xFFFFu;
#else
    unsigned r;
    asm("v_cvt_pk_fp8_f32 %0, %1, %2" : "=v"(r) : "v"(a), "v"(b));
    return r & 0xFFFFu;
#endif
}

// ---------- fp8 e4m3 decode: f16-pk builtin > f32-pk builtin > f32-pk asm ----------
#if __has_builtin(__builtin_amdgcn_cvt_pk_f16_fp8)
#define EDGE_PATH 0
#define YSC 1.0f
static __device__ inline h16x2 dec2lo(unsigned v) {
    return __builtin_amdgcn_cvt_pk_f16_fp8((short)v);
}
static __device__ inline h16x2 dec2hi(unsigned v) {
    return __builtin_amdgcn_cvt_pk_f16_fp8((short)(v >> 16));
}
static __device__ inline h16x2 reluh(h16x2 v) {
#if __has_builtin(__builtin_elementwise_max)
    h16x2 z = { (_Float16)0.0f, (_Float16)0.0f };
    return __builtin_elementwise_max(v, z);
#else
    unsigned u = __builtin_bit_cast(unsigned, v);
    unsigned m = ((u >> 15) & 0x00010001u) * 0xFFFFu;
    u &= ~m;
    return __builtin_bit_cast(h16x2, u);
#endif
}
static __device__ inline float dot2acc(h16x2 a, h16x2 b, float c) {
#if __has_builtin(__builtin_amdgcn_fdot2)
    return __builtin_amdgcn_fdot2(a, b, c, false);
#else
    return c + (float)a[0] * (float)b[0] + (float)a[1] * (float)b[1];
#endif
}
#else
#define EDGE_PATH 1
#if __has_builtin(__builtin_amdgcn_cvt_pk_f32_fp8)
static __device__ inline f32x2 d32lo(unsigned v) {
    return __builtin_amdgcn_cvt_pk_f32_fp8((int)v, false);
}
static __device__ inline f32x2 d32hi(unsigned v) {
    return __builtin_amdgcn_cvt_pk_f32_fp8((int)v, true);
}
#else
static __device__ inline f32x2 d32lo(unsigned v) {
    f32x2 r;
    asm("v_cvt_pk_f32_fp8 %0, %1" : "=v"(r) : "v"(v));
    return r;
}
static __device__ inline f32x2 d32hi(unsigned v) {
    f32x2 r;
    unsigned s = v >> 16;
    asm("v_cvt_pk_f32_fp8 %0, %1" : "=v"(r) : "v"(s));
    return r;
}
#endif
#endif

// ---------------- Phase A: barrier-free Y^T MFMA, direct global x frags ----------------
#define GRIDA 768   // 3 blocks/CU x 256 CUs

__global__ __launch_bounds__(256, 3) void precompute_kernel(
    const float* __restrict__ x,    // [N,128]
    const float* __restrict__ W1,   // [128,256]
    const float* __restrict__ b1,   // [128]
    unsigned char* __restrict__ Y8, // [N,256] fp8 e4m3
    int N, int ntiles)
{
    const int tid  = threadIdx.x;
    const int wid  = tid >> 6;                   // wave id = 64-feature col slice
    const int lane = tid & 63;
    const int quad = lane >> 4, l15 = lane & 15;
    const int cs   = wid;

    // ---- W1 bf16 A-frags (prologue, once per block; asm cvt)
    // frag (c,j): lane -> W1row[o=cs*64+j*16+l15][k=c*32+quad*8 .. +8]
    s16x8 bf[4][4];   // [k-chunk][col-tile]
    #pragma unroll
    for (int j = 0; j < 4; ++j) {
        #pragma unroll
        for (int c = 0; c < 4; ++c) {
            int o  = cs * 64 + j * 16 + l15;
            int kb = c * 32 + quad * 8;
            const float* wp = W1 + (size_t)(o & 127) * 256 + (o >> 7) * 128 + kb;
            f32x4 u0 = *(const f32x4*)wp;
            f32x4 u1 = *(const f32x4*)(wp + 4);
            u32x4 pk;
            pk[0] = pkbf16(u0[0], u0[1]);
            pk[1] = pkbf16(u0[2], u0[3]);
            pk[2] = pkbf16(u1[0], u1[1]);
            pk[3] = pkbf16(u1[2], u1[3]);
            bf[c][j] = __builtin_bit_cast(s16x8, pk);
        }
    }

    const bool qb0 = (quad & 1), qb1 = (quad & 2);

    for (int t = blockIdx.x; t < ntiles; t += GRIDA) {
        const int m0 = t * 32;

        // ---- acc init = bias (folded; left half only; b1 is L1-hot)
        f32x4 acc[2][4];
        #pragma unroll
        for (int j = 0; j < 4; ++j) {
            f32x4 bi = (cs < 2) ? *(const f32x4*)&b1[cs * 64 + j * 16 + quad * 4]
                                : (f32x4){0.f, 0.f, 0.f, 0.f};
            acc[0][j] = bi; acc[1][j] = bi;
        }

        // ---- per 16-node group: B-frags straight from global x (f32),
        //      convert in-reg, 16 MFMA. No LDS, no barrier, no vmcnt drain.
        #pragma unroll
        for (int i2 = 0; i2 < 2; ++i2) {
            int m = m0 + i2 * 16 + l15; if (m >= N) m = N - 1;
            const float* xr = x + (size_t)m * D + quad * 8;
            s16x8 af[4];
            #pragma unroll
            for (int c = 0; c < 4; ++c) {
                f32x4 lo = *(const f32x4*)(xr + c * 32);
                f32x4 hi = *(const f32x4*)(xr + c * 32 + 4);
                u32x4 pk;
                pk[0] = pkbf16(lo[0], lo[1]);
                pk[1] = pkbf16(lo[2], lo[3]);
                pk[2] = pkbf16(hi[0], hi[1]);
                pk[3] = pkbf16(hi[2], hi[3]);
                af[c] = __builtin_bit_cast(s16x8, pk);
            }
            #pragma unroll
            for (int c = 0; c < 4; ++c)
                #pragma unroll
                for (int j = 0; j < 4; ++j)
                    acc[i2][j] = __builtin_amdgcn_mfma_f32_16x16x32_bf16(
                        bf[c][j], af[c], acc[i2][j], 0, 0, 0);
        }

        // ---- epilogue: fp8 encode from acc + 4x4 quad transpose -> 16B stores
        // D layout: col=l15 -> node (m0+i2*16+l15), row=quad*4+r -> feature
        // (cs*64 + j*16 + quad*4 + r). dw[j] = one fp8 dword.
        #pragma unroll
        for (int i2 = 0; i2 < 2; ++i2) {
            unsigned dw[4];
            #pragma unroll
            for (int j = 0; j < 4; ++j) {
                f32x4 v = acc[i2][j];
                dw[j] = enc2(v[0], v[1]) | (enc2(v[2], v[3]) << 16);
            }
            // transpose across quads (lanes +-16/+-32): lane q ends with
            // {dw[q] of quad 0..3} = 16 consecutive features at col cs*64+q*16
            unsigned s01 = qb0 ? dw[0] : dw[1];
            unsigned r01 = __shfl_xor(s01, 16);
            unsigned s23 = qb0 ? dw[2] : dw[3];
            unsigned r23 = __shfl_xor(s23, 16);
            unsigned a0 = qb0 ? r01 : dw[0];
            unsigned a1 = qb0 ? dw[1] : r01;
            unsigned a2 = qb0 ? r23 : dw[2];
            unsigned a3 = qb0 ? dw[3] : r23;
            unsigned s02 = qb1 ? a0 : a2;
            unsigned r02 = __shfl_xor(s02, 32);
            unsigned s13 = qb1 ? a1 : a3;
            unsigned r13 = __shfl_xor(s13, 32);
            uint4 ov;
            ov.x = qb1 ? r02 : a0;
            ov.y = qb1 ? r13 : a1;
            ov.z = qb1 ? a2 : r02;
            ov.w = qb1 ? a3 : r13;
            int m = m0 + i2 * 16 + l15;
            if (m < N)
                *(uint4*)(Y8 + (size_t)m * 256 + cs * 64 + quad * 16) = ov;
        }
    }
}

// ---------------- Phase B: 8 edges per 8-lane group, fp8 gather ----------------
#define EPB 256   // edges per block (256 threads, 32 groups x 8 edges)

__global__ __launch_bounds__(256, 4) void edge_kernel(
    const unsigned char* __restrict__ Y8,  // [N,256] fp8
    const int*           __restrict__ ei,  // [2,E]
    const float*         __restrict__ W2,  // [128]
    const float*         __restrict__ b2,  // [1]
    float*               __restrict__ out, // [E]
    int E)
{
    __shared__ int eis[2][EPB];                 // [src/dst][edge-in-block]

    const int tid = threadIdx.x;
    const int sub = tid & 7;                    // 8 lanes per edge
    const int grp = tid >> 3;                   // 0..31
    const int e0b = blockIdx.x * EPB;

    // ---- coalesced ei stage: each thread loads one src + one dst index
    {
        int e = e0b + tid;
        eis[0][tid] = (e < E) ? ei[e] : 0;
        eis[1][tid] = (e < E) ? ei[(size_t)E + e] : 0;
    }
    __syncthreads();

    // ---- W2 for this sub-lane's 16 columns
#if EDGE_PATH == 1
    f32x2 w2f[8];
    {
        const float* wp = &W2[sub * 16];
        #pragma unroll
        for (int q = 0; q < 8; ++q)
            w2f[q] = *(const f32x2*)(wp + q * 2);
    }
#else
    h16x2 w2h[8];
    {
        const float* wp = &W2[sub * 16];
        #pragma unroll
        for (int q = 0; q < 8; ++q) {
            float2 f = *(const float2*)(wp + q * 2);
            w2h[q] = (h16x2){ (_Float16)(f.x * YSC), (_Float16)(f.y * YSC) };
        }
    }
#endif

    // ---- issue ALL 16 gather segments before any decode (MLP=16/thread)
    uint4 L[8], R[8];
    #pragma unroll
    for (int k = 0; k < 8; ++k) {
        int ib  = grp + 32 * k;
        int src = eis[0][ib];
        int dst = eis[1][ib];
        L[k] = *(const uint4*)(Y8 + (size_t)src * 256 + sub * 16);
        R[k] = *(const uint4*)(Y8 + (size_t)dst * 256 + 128 + sub * 16);
    }

    float s[8] = { 0.f, 0.f, 0.f, 0.f, 0.f, 0.f, 0.f, 0.f };
    #pragma unroll
    for (int k = 0; k < 8; ++k) {
        const unsigned* a = (const unsigned*)&L[k];
        const unsigned* c = (const unsigned*)&R[k];
        #pragma unroll
        for (int d = 0; d < 4; ++d) {
#if EDGE_PATH == 1
            f32x2 zl = d32lo(a[d]) + d32lo(c[d]);
            f32x2 zh = d32hi(a[d]) + d32hi(c[d]);
            s[k] = fmaf(fmaxf(zl[0], 0.f), w2f[2*d][0], s[k]);
            s[k] = fmaf(fmaxf(zl[1], 0.f), w2f[2*d][1], s[k]);
            s[k] = fmaf(fmaxf(zh[0], 0.f), w2f[2*d + 1][0], s[k]);
            s[k] = fmaf(fmaxf(zh[1], 0.f), w2f[2*d + 1][1], s[k]);
#else
            h16x2 za = reluh(dec2lo(a[d]) + dec2lo(c[d]));
            s[k] = dot2acc(za, w2h[2*d],     s[k]);
            h16x2 zb = reluh(dec2hi(a[d]) + dec2hi(c[d]));
            s[k] = dot2acc(zb, w2h[2*d + 1], s[k]);
#endif
        }
    }

    #pragma unroll
    for (int k = 0; k < 8; ++k) {
        s[k] += __shfl_xor(s[k], 1);
        s[k] += __shfl_xor(s[k], 2);
        s[k] += __shfl_xor(s[k], 4);
    }

    if (sub == 0) {
        float bb = b2[0];
        #pragma unroll
        for (int k = 0; k < 8; ++k) {
            int e = e0b + grp + 32 * k;
            if (e < E) {
                float t = fmaxf(s[k] + bb, 0.f);
                out[e] = 1.0f / (1.0f + expf(-t));
            }
        }
    }
}

// ---------------- fallback (fused edge-wise GEMM, fp32 inputs) ----------------
#define BM   128
#define BK   64
#define LDT  72

__global__ __launch_bounds__(256) void decoder_fallback_kernel(
    const float* __restrict__ x, const int* __restrict__ ei,
    const float* __restrict__ W1, const float* __restrict__ b1,
    const float* __restrict__ W2, const float* __restrict__ b2,
    float* __restrict__ out, int E)
{
    __shared__ int   nid[2][BM];
    __shared__ short At[BM * LDT];
    __shared__ short Bt[D * LDT];
    __shared__ float rowsum[BM][2];

    const int tid = threadIdx.x;
    const int e0  = blockIdx.x * BM;
    if (tid < BM) { int e = e0 + tid; nid[0][tid] = (e < E) ? ei[e] : 0; }
    else { int e = e0 + (tid - BM); nid[1][tid - BM] = (e < E) ? ei[E + e] : 0; }

    const int wid = tid >> 6, lane = tid & 63;
    const int wm = wid >> 1, wn = wid & 1;
    const int quad = lane >> 4, l15 = lane & 15;
    const int srow = tid >> 4, scol = (tid & 15) * 4;
    f32x4 acc[4][4] = {};
    __syncthreads();

    for (int t = 0; t < 4; ++t) {
        const int* ids = nid[t >> 1];
        const int kx = (t & 1) * BK, kw = t * BK;
        #pragma unroll
        for (int p = 0; p < 8; ++p) {
            int row = srow + p * 16;
            float4 v = *(const float4*)&x[(size_t)ids[row] * D + kx + scol];
            s16x4 bv = { f2bf(v.x), f2bf(v.y), f2bf(v.z), f2bf(v.w) };
            *(s16x4*)&At[row * LDT + scol] = bv;
        }
        #pragma unroll
        for (int p = 0; p < 8; ++p) {
            int n = srow + p * 16;
            float4 v = *(const float4*)&W1[n * 256 + kw + scol];
            s16x4 bv = { f2bf(v.x), f2bf(v.y), f2bf(v.z), f2bf(v.w) };
            *(s16x4*)&Bt[n * LDT + scol] = bv;
        }
        __syncthreads();
        #pragma unroll
        for (int c = 0; c < 2; ++c) {
            const int kc = c * 32;
            s16x8 af[4], bfr[4];
            #pragma unroll
            for (int i = 0; i < 4; ++i)
                af[i] = *(const s16x8*)&At[(wm*64 + i*16 + l15) * LDT + kc + quad*8];
            #pragma unroll
            for (int j = 0; j < 4; ++j)
                bfr[j] = *(const s16x8*)&Bt[(wn*64 + j*16 + l15) * LDT + kc + quad*8];
            #pragma unroll
            for (int i = 0; i < 4; ++i)
                #pragma unroll
                for (int j = 0; j < 4; ++j)
                    acc[i][j] = __builtin_amdgcn_mfma_f32_16x16x32_bf16(
                        af[i], bfr[j], acc[i][j], 0, 0, 0);
        }
        __syncthreads();
    }
    float b1v[4], w2v[4];
    #pragma unroll
    for (int j = 0; j < 4; ++j) {
        int col = wn*64 + j*16 + l15;
        b1v[j] = b1[col]; w2v[j] = W2[col];
    }
    float psum[16];
    #pragma unroll
    for (int t = 0; t < 16; ++t) psum[t] = 0.f;
    #pragma unroll
    for (int i = 0; i < 4; ++i)
        #pragma unroll
        for (int j = 0; j < 4; ++j)
            #pragma unroll
            for (int r = 0; r < 4; ++r) {
                float c = fmaxf(acc[i][j][r] + b1v[j], 0.f);
                psum[i*4 + r] += c * w2v[j];
            }
    #pragma unroll
    for (int off = 1; off < 16; off <<= 1)
        #pragma unroll
        for (int t = 0; t < 16; ++t)
            psum[t] += __shfl_xor(psum[t], off);
    if (l15 == 0) {
        #pragma unroll
        for (int i = 0; i < 4; ++i)
            #pragma unroll
            for (int r = 0; r < 4; ++r)
                rowsum[wm*64 + i*16 + quad*4 + r][wn] = psum[i*4 + r];
    }
    __syncthreads();
    if (tid < BM) {
        int e = e0 + tid;
        if (e < E) {
            float s = rowsum[tid][0] + rowsum[tid][1] + b2[0];
            s = fmaxf(s, 0.f);
            out[e] = 1.0f / (1.0f + expf(-s));
        }
    }
}

extern "C" void kernel_launch(void* const* d_in, const int* in_sizes, int n_in,
                              void* d_out, int out_size, void* d_ws, size_t ws_size,
                              hipStream_t stream) {
    const float* x  = (const float*)d_in[0];
    const int*   ei = (const int*)d_in[1];
    const float* W1 = (const float*)d_in[2];
    const float* b1 = (const float*)d_in[3];
    const float* W2 = (const float*)d_in[4];
    const float* b2 = (const float*)d_in[5];
    float* out = (float*)d_out;

    int E = in_sizes[1] / 2;
    int N = in_sizes[0] / D;

    size_t y_bytes = (size_t)N * 256;                    // 25.6 MB fp8
    if (ws_size >= y_bytes) {
        unsigned char* Y8 = (unsigned char*)d_ws;
        int ntiles = (N + 31) / 32;
        int gridA  = (ntiles < GRIDA) ? ntiles : GRIDA;  // 3 blocks/CU, grid-stride
        precompute_kernel<<<gridA, 256, 0, stream>>>(x, W1, b1, Y8, N, ntiles);
        int gridB = (E + EPB - 1) / EPB;
        edge_kernel<<<gridB, 256, 0, stream>>>(Y8, ei, W2, b2, out, E);
    } else {
        int nblocks = (E + BM - 1) / BM;
        decoder_fallback_kernel<<<nblocks, 256, 0, stream>>>(
            x, ei, W1, b1, W2, b2, out, E);
    }
}

// Round 10
// 130.739 us; speedup vs baseline: 1.1843x; 1.1641x over previous
//
#include <hip/hip_runtime.h>
#include <hip/hip_bf16.h>
#include <hip/hip_fp16.h>
#include <math.h>

// Decoder: out[e] = sigmoid(relu( W2 . relu( W1 * [x[src]; x[dst]] + b1 ) + b2 ))
// Factorized: Y[n][0:128] = W1_left*x[n] + b1 ; Y[n][128:256] = W1_right*x[n]
//             out[e] = sigmoid(relu( W2 . relu(Yl[src]+Yr[dst]) + b2 ))
// Y stored fp8 e4m3 (25.6 MB).
// LEDGER: fills+gaps 86.3 | pre: R12-struct 22.6 (R17), barrier-free 50.7
// (R18 PMC: latency-bound, Occ 27%, 1 TB/s -> staging+prefetch was load-
// bearing) | edge: sw-decode 22-23, asm-f32-decode 15.2 (R18 algebra; fp8
// cvt builtins ABSENT on this toolchain -> asm is the fix).
// R19: (a) precompute reverted to R12 dataflow (gload_lds + both-sides XOR
// swizzle + LDS reads + MFMA + quad-transpose epilogue) keeping asm enc2 +
// pkbf16; (b) R12's per-iter vmcnt(0)+__syncthreads full-drain replaced by
// m201-style counted-vmcnt + raw s_barrier: 3-buffer ring, 2-deep prefetch,
// per-wave symmetric waits (first=vmcnt(4), steady=vmcnt(6), tail=vmcnt(2);
// stage=4 vm-ops, stores=2 vm-ops/iter; b1 hoisted so counts are wave-
// uniform; N%32==0 so no store divergence). Edge kernel = R18 verbatim.

typedef short    s16x4 __attribute__((ext_vector_type(4)));
typedef short    s16x8 __attribute__((ext_vector_type(8)));
typedef float    f32x2 __attribute__((ext_vector_type(2)));
typedef float    f32x4 __attribute__((ext_vector_type(4)));
typedef unsigned u32x4 __attribute__((ext_vector_type(4)));
typedef _Float16 h16x2 __attribute__((ext_vector_type(2)));

#define D 128

static __device__ inline short f2bf(float f) {
    unsigned u = __builtin_bit_cast(unsigned, f);
    unsigned r = (u + 0x7FFFu + ((u >> 16) & 1u)) >> 16;
    return (short)r;
}

// f32 pair -> packed bf16 dword (RNE), gfx950
static __device__ inline unsigned pkbf16(float a, float b) {
    unsigned r;
    asm("v_cvt_pk_bf16_f32 %0, %1, %2" : "=v"(r) : "v"(a), "v"(b));
    return r;
}

// async global->LDS 16B; LDS dest = wave-uniform base + lane*16 (m104)
static __device__ inline void stage16(const void* g, void* l) {
    __builtin_amdgcn_global_load_lds(
        (const __attribute__((address_space(1))) void*)g,
        (__attribute__((address_space(3))) void*)l, 16, 0, 0);
}

// ---------- fp8 e4m3 encode: builtin or direct asm (builtins absent here) ----------
static __device__ inline unsigned enc2(float a, float b) {
#if __has_builtin(__builtin_amdgcn_cvt_pk_fp8_f32)
    return ((unsigned)__builtin_amdgcn_cvt_pk_fp8_f32(a, b, 0, false)) & 0xFFFFu;
#else
    unsigned r;
    asm("v_cvt_pk_fp8_f32 %0, %1, %2" : "=v"(r) : "v"(a), "v"(b));
    return r & 0xFFFFu;
#endif
}

// ---------- fp8 e4m3 decode: f16-pk builtin > f32-pk builtin > f32-pk asm ----------
#if __has_builtin(__builtin_amdgcn_cvt_pk_f16_fp8)
#define EDGE_PATH 0
#define YSC 1.0f
static __device__ inline h16x2 dec2lo(unsigned v) {
    return __builtin_amdgcn_cvt_pk_f16_fp8((short)v);
}
static __device__ inline h16x2 dec2hi(unsigned v) {
    return __builtin_amdgcn_cvt_pk_f16_fp8((short)(v >> 16));
}
static __device__ inline h16x2 reluh(h16x2 v) {
#if __has_builtin(__builtin_elementwise_max)
    h16x2 z = { (_Float16)0.0f, (_Float16)0.0f };
    return __builtin_elementwise_max(v, z);
#else
    unsigned u = __builtin_bit_cast(unsigned, v);
    unsigned m = ((u >> 15) & 0x00010001u) * 0xFFFFu;
    u &= ~m;
    return __builtin_bit_cast(h16x2, u);
#endif
}
static __device__ inline float dot2acc(h16x2 a, h16x2 b, float c) {
#if __has_builtin(__builtin_amdgcn_fdot2)
    return __builtin_amdgcn_fdot2(a, b, c, false);
#else
    return c + (float)a[0] * (float)b[0] + (float)a[1] * (float)b[1];
#endif
}
#else
#define EDGE_PATH 1
#if __has_builtin(__builtin_amdgcn_cvt_pk_f32_fp8)
static __device__ inline f32x2 d32lo(unsigned v) {
    return __builtin_amdgcn_cvt_pk_f32_fp8((int)v, false);
}
static __device__ inline f32x2 d32hi(unsigned v) {
    return __builtin_amdgcn_cvt_pk_f32_fp8((int)v, true);
}
#else
static __device__ inline f32x2 d32lo(unsigned v) {
    f32x2 r;
    asm("v_cvt_pk_f32_fp8 %0, %1" : "=v"(r) : "v"(v));
    return r;
}
static __device__ inline f32x2 d32hi(unsigned v) {
    f32x2 r;
    unsigned s = v >> 16;
    asm("v_cvt_pk_f32_fp8 %0, %1" : "=v"(r) : "v"(s));
    return r;
}
#endif
#endif

// ---------------- Phase A: Y^T MFMA, gload_lds staging, counted-vmcnt ring ----------------
#define GRIDA 768   // 3 blocks/CU x 256 CUs

__global__ __launch_bounds__(256, 3) void precompute_kernel(
    const float* __restrict__ x,    // [N,128]
    const float* __restrict__ W1,   // [128,256]
    const float* __restrict__ b1,   // [128]
    unsigned char* __restrict__ Y8, // [N,256] fp8 e4m3
    int N, int ntiles)
{
    // 3 x 32 rows x 512B ring; rows XOR-swizzled by ((row&7)<<4) on both sides
    __shared__ float Xt[3][32 * 128];

    const int tid  = threadIdx.x;
    const int wid  = tid >> 6;                   // wave id = 64-feature col slice
    const int lane = tid & 63;
    const int quad = lane >> 4, l15 = lane & 15;
    const int cs   = wid;

    // ---- W1 bf16 A-frags (prologue, once per block; asm cvt)
    s16x8 bf[4][4];   // [k-chunk][col-tile]
    #pragma unroll
    for (int j = 0; j < 4; ++j) {
        #pragma unroll
        for (int c = 0; c < 4; ++c) {
            int o  = cs * 64 + j * 16 + l15;
            int kb = c * 32 + quad * 8;
            const float* wp = W1 + (size_t)(o & 127) * 256 + (o >> 7) * 128 + kb;
            f32x4 u0 = *(const f32x4*)wp;
            f32x4 u1 = *(const f32x4*)(wp + 4);
            u32x4 pk;
            pk[0] = pkbf16(u0[0], u0[1]);
            pk[1] = pkbf16(u0[2], u0[3]);
            pk[2] = pkbf16(u1[0], u1[1]);
            pk[3] = pkbf16(u1[2], u1[3]);
            bf[c][j] = __builtin_bit_cast(s16x8, pk);
        }
    }

    // ---- b1 hoisted OUT of the loop (keeps per-iter vmcnt counts uniform)
    f32x4 b1v[4];
    #pragma unroll
    for (int j = 0; j < 4; ++j)
        b1v[j] = (cs < 2) ? *(const f32x4*)&b1[cs * 64 + j * 16 + quad * 4]
                          : (f32x4){0.f, 0.f, 0.f, 0.f};

    // staging geometry: per wave 4 x stage16 = 4 vmcnt ops covering its 4KB
    const int rl   = wid * 2 + (lane >> 5);      // row = i*8 + rl
    const int colb = (lane & 31) * 16;           // in-row byte offset (pre-swizzle)
    const char* xbytes = (const char*)x;

    auto stage_tile = [&](int tt, int bb) {
        char* lb = (char*)&Xt[bb][0] + wid * 1024;   // wave-uniform base
        #pragma unroll
        for (int i = 0; i < 4; ++i) {
            int row = i * 8 + rl;
            int m = tt * 32 + row; if (m >= N) m = N - 1;
            stage16(xbytes + (size_t)m * 512 + (colb ^ ((row & 7) << 4)),
                    lb + i * 4096);
        }
    };

    const int t0 = blockIdx.x;
    if (t0 < ntiles)         stage_tile(t0, 0);
    if (t0 + GRIDA < ntiles) stage_tile(t0 + GRIDA, 1);

    const int swz = (l15 & 7) << 4;              // read-side swizzle
    const bool qb0 = (quad & 1), qb1 = (quad & 2);

    int it = 0;
    for (int t = t0; t < ntiles; t += GRIDA, ++it) {
        const bool hasnext = (t + GRIDA < ntiles);
        // ---- counted drain of OWN stage(t) ops (4), leave newer in flight:
        // queue newer-than-stage(t): steady = stores(prev):2 + stage(t+1):4 = 6
        //                            first  = stage(t+1):4 ; tail = stores:2
        if (it == 0) {
            if (hasnext) asm volatile("s_waitcnt vmcnt(4)" ::: "memory");
            else         asm volatile("s_waitcnt vmcnt(0)" ::: "memory");
        } else {
            if (hasnext) asm volatile("s_waitcnt vmcnt(6)" ::: "memory");
            else         asm volatile("s_waitcnt vmcnt(2)" ::: "memory");
        }
        // symmetric per-wave waits + raw barrier => all waves' stage(t) landed
        asm volatile("s_barrier" ::: "memory");

        const int buf = it % 3;

        // ---- acc init = bias (from regs)
        f32x4 acc[2][4];
        #pragma unroll
        for (int j = 0; j < 4; ++j) { acc[0][j] = b1v[j]; acc[1][j] = b1v[j]; }

        // ---- read x frags from swizzled LDS, convert f32->bf16 in-reg
        s16x8 af[2][4];   // [i2][c]
        {
            const char* xb8 = (const char*)&Xt[buf][0];
            #pragma unroll
            for (int i2 = 0; i2 < 2; ++i2) {
                const char* rp = xb8 + (i2 * 16 + l15) * 512;
                #pragma unroll
                for (int c = 0; c < 4; ++c) {
                    int kb = c * 128 + quad * 32;
                    f32x4 lo = *(const f32x4*)(rp + ( kb       ^ swz));
                    f32x4 hi = *(const f32x4*)(rp + ((kb + 16) ^ swz));
                    u32x4 pk;
                    pk[0] = pkbf16(lo[0], lo[1]);
                    pk[1] = pkbf16(lo[2], lo[3]);
                    pk[2] = pkbf16(hi[0], hi[1]);
                    pk[3] = pkbf16(hi[2], hi[3]);
                    af[i2][c] = __builtin_bit_cast(s16x8, pk);
                }
            }
        }

        // ---- MFMA: D = W1frag x xfrag = Y^T (row=feature, col=node)
        #pragma unroll
        for (int c = 0; c < 4; ++c)
            #pragma unroll
            for (int i2 = 0; i2 < 2; ++i2)
                #pragma unroll
                for (int j = 0; j < 4; ++j)
                    acc[i2][j] = __builtin_amdgcn_mfma_f32_16x16x32_bf16(
                        bf[c][j], af[i2][c], acc[i2][j], 0, 0, 0);

        // ---- epilogue: fp8 encode + 4x4 quad transpose -> 16B stores (2 vm ops)
        const int m0 = t * 32;
        #pragma unroll
        for (int i2 = 0; i2 < 2; ++i2) {
            unsigned dw[4];
            #pragma unroll
            for (int j = 0; j < 4; ++j) {
                f32x4 v = acc[i2][j];
                dw[j] = enc2(v[0], v[1]) | (enc2(v[2], v[3]) << 16);
            }
            unsigned s01 = qb0 ? dw[0] : dw[1];
            unsigned r01 = __shfl_xor(s01, 16);
            unsigned s23 = qb0 ? dw[2] : dw[3];
            unsigned r23 = __shfl_xor(s23, 16);
            unsigned a0 = qb0 ? r01 : dw[0];
            unsigned a1 = qb0 ? dw[1] : r01;
            unsigned a2 = qb0 ? r23 : dw[2];
            unsigned a3 = qb0 ? dw[3] : r23;
            unsigned s02 = qb1 ? a0 : a2;
            unsigned r02 = __shfl_xor(s02, 32);
            unsigned s13 = qb1 ? a1 : a3;
            unsigned r13 = __shfl_xor(s13, 32);
            uint4 ov;
            ov.x = qb1 ? r02 : a0;
            ov.y = qb1 ? r13 : a1;
            ov.z = qb1 ? a2 : r02;
            ov.w = qb1 ? a3 : r13;
            int m = m0 + i2 * 16 + l15;
            if (m < N)
                *(uint4*)(Y8 + (size_t)m * 256 + cs * 64 + quad * 16) = ov;
        }

        // ---- stage tile t+2G into ring slot (it+2)%3; safe: that slot was
        // read at iter it-1, and this point is after iter-it's barrier.
        if (t + 2 * GRIDA < ntiles) stage_tile(t + 2 * GRIDA, (it + 2) % 3);
    }
}

// ---------------- Phase B: 8 edges per 8-lane group, fp8 gather (R18) ----------------
#define EPB 256   // edges per block (256 threads, 32 groups x 8 edges)

__global__ __launch_bounds__(256, 4) void edge_kernel(
    const unsigned char* __restrict__ Y8,  // [N,256] fp8
    const int*           __restrict__ ei,  // [2,E]
    const float*         __restrict__ W2,  // [128]
    const float*         __restrict__ b2,  // [1]
    float*               __restrict__ out, // [E]
    int E)
{
    __shared__ int eis[2][EPB];                 // [src/dst][edge-in-block]

    const int tid = threadIdx.x;
    const int sub = tid & 7;                    // 8 lanes per edge
    const int grp = tid >> 3;                   // 0..31
    const int e0b = blockIdx.x * EPB;

    {
        int e = e0b + tid;
        eis[0][tid] = (e < E) ? ei[e] : 0;
        eis[1][tid] = (e < E) ? ei[(size_t)E + e] : 0;
    }
    __syncthreads();

#if EDGE_PATH == 1
    f32x2 w2f[8];
    {
        const float* wp = &W2[sub * 16];
        #pragma unroll
        for (int q = 0; q < 8; ++q)
            w2f[q] = *(const f32x2*)(wp + q * 2);
    }
#else
    h16x2 w2h[8];
    {
        const float* wp = &W2[sub * 16];
        #pragma unroll
        for (int q = 0; q < 8; ++q) {
            float2 f = *(const float2*)(wp + q * 2);
            w2h[q] = (h16x2){ (_Float16)(f.x * YSC), (_Float16)(f.y * YSC) };
        }
    }
#endif

    uint4 L[8], R[8];
    #pragma unroll
    for (int k = 0; k < 8; ++k) {
        int ib  = grp + 32 * k;
        int src = eis[0][ib];
        int dst = eis[1][ib];
        L[k] = *(const uint4*)(Y8 + (size_t)src * 256 + sub * 16);
        R[k] = *(const uint4*)(Y8 + (size_t)dst * 256 + 128 + sub * 16);
    }

    float s[8] = { 0.f, 0.f, 0.f, 0.f, 0.f, 0.f, 0.f, 0.f };
    #pragma unroll
    for (int k = 0; k < 8; ++k) {
        const unsigned* a = (const unsigned*)&L[k];
        const unsigned* c = (const unsigned*)&R[k];
        #pragma unroll
        for (int d = 0; d < 4; ++d) {
#if EDGE_PATH == 1
            f32x2 zl = d32lo(a[d]) + d32lo(c[d]);
            f32x2 zh = d32hi(a[d]) + d32hi(c[d]);
            s[k] = fmaf(fmaxf(zl[0], 0.f), w2f[2*d][0], s[k]);
            s[k] = fmaf(fmaxf(zl[1], 0.f), w2f[2*d][1], s[k]);
            s[k] = fmaf(fmaxf(zh[0], 0.f), w2f[2*d + 1][0], s[k]);
            s[k] = fmaf(fmaxf(zh[1], 0.f), w2f[2*d + 1][1], s[k]);
#else
            h16x2 za = reluh(dec2lo(a[d]) + dec2lo(c[d]));
            s[k] = dot2acc(za, w2h[2*d],     s[k]);
            h16x2 zb = reluh(dec2hi(a[d]) + dec2hi(c[d]));
            s[k] = dot2acc(zb, w2h[2*d + 1], s[k]);
#endif
        }
    }

    #pragma unroll
    for (int k = 0; k < 8; ++k) {
        s[k] += __shfl_xor(s[k], 1);
        s[k] += __shfl_xor(s[k], 2);
        s[k] += __shfl_xor(s[k], 4);
    }

    if (sub == 0) {
        float bb = b2[0];
        #pragma unroll
        for (int k = 0; k < 8; ++k) {
            int e = e0b + grp + 32 * k;
            if (e < E) {
                float t = fmaxf(s[k] + bb, 0.f);
                out[e] = 1.0f / (1.0f + expf(-t));
            }
        }
    }
}

// ---------------- fallback (fused edge-wise GEMM, fp32 inputs) ----------------
#define BM   128
#define BK   64
#define LDT  72

__global__ __launch_bounds__(256) void decoder_fallback_kernel(
    const float* __restrict__ x, const int* __restrict__ ei,
    const float* __restrict__ W1, const float* __restrict__ b1,
    const float* __restrict__ W2, const float* __restrict__ b2,
    float* __restrict__ out, int E)
{
    __shared__ int   nid[2][BM];
    __shared__ short At[BM * LDT];
    __shared__ short Bt[D * LDT];
    __shared__ float rowsum[BM][2];

    const int tid = threadIdx.x;
    const int e0  = blockIdx.x * BM;
    if (tid < BM) { int e = e0 + tid; nid[0][tid] = (e < E) ? ei[e] : 0; }
    else { int e = e0 + (tid - BM); nid[1][tid - BM] = (e < E) ? ei[E + e] : 0; }

    const int wid = tid >> 6, lane = tid & 63;
    const int wm = wid >> 1, wn = wid & 1;
    const int quad = lane >> 4, l15 = lane & 15;
    const int srow = tid >> 4, scol = (tid & 15) * 4;
    f32x4 acc[4][4] = {};
    __syncthreads();

    for (int t = 0; t < 4; ++t) {
        const int* ids = nid[t >> 1];
        const int kx = (t & 1) * BK, kw = t * BK;
        #pragma unroll
        for (int p = 0; p < 8; ++p) {
            int row = srow + p * 16;
            float4 v = *(const float4*)&x[(size_t)ids[row] * D + kx + scol];
            s16x4 bv = { f2bf(v.x), f2bf(v.y), f2bf(v.z), f2bf(v.w) };
            *(s16x4*)&At[row * LDT + scol] = bv;
        }
        #pragma unroll
        for (int p = 0; p < 8; ++p) {
            int n = srow + p * 16;
            float4 v = *(const float4*)&W1[n * 256 + kw + scol];
            s16x4 bv = { f2bf(v.x), f2bf(v.y), f2bf(v.z), f2bf(v.w) };
            *(s16x4*)&Bt[n * LDT + scol] = bv;
        }
        __syncthreads();
        #pragma unroll
        for (int c = 0; c < 2; ++c) {
            const int kc = c * 32;
            s16x8 af[4], bfr[4];
            #pragma unroll
            for (int i = 0; i < 4; ++i)
                af[i] = *(const s16x8*)&At[(wm*64 + i*16 + l15) * LDT + kc + quad*8];
            #pragma unroll
            for (int j = 0; j < 4; ++j)
                bfr[j] = *(const s16x8*)&Bt[(wn*64 + j*16 + l15) * LDT + kc + quad*8];
            #pragma unroll
            for (int i = 0; i < 4; ++i)
                #pragma unroll
                for (int j = 0; j < 4; ++j)
                    acc[i][j] = __builtin_amdgcn_mfma_f32_16x16x32_bf16(
                        af[i], bfr[j], acc[i][j], 0, 0, 0);
        }
        __syncthreads();
    }
    float b1v[4], w2v[4];
    #pragma unroll
    for (int j = 0; j < 4; ++j) {
        int col = wn*64 + j*16 + l15;
        b1v[j] = b1[col]; w2v[j] = W2[col];
    }
    float psum[16];
    #pragma unroll
    for (int t = 0; t < 16; ++t) psum[t] = 0.f;
    #pragma unroll
    for (int i = 0; i < 4; ++i)
        #pragma unroll
        for (int j = 0; j < 4; ++j)
            #pragma unroll
            for (int r = 0; r < 4; ++r) {
                float c = fmaxf(acc[i][j][r] + b1v[j], 0.f);
                psum[i*4 + r] += c * w2v[j];
            }
    #pragma unroll
    for (int off = 1; off < 16; off <<= 1)
        #pragma unroll
        for (int t = 0; t < 16; ++t)
            psum[t] += __shfl_xor(psum[t], off);
    if (l15 == 0) {
        #pragma unroll
        for (int i = 0; i < 4; ++i)
            #pragma unroll
            for (int r = 0; r < 4; ++r)
                rowsum[wm*64 + i*16 + quad*4 + r][wn] = psum[i*4 + r];
    }
    __syncthreads();
    if (tid < BM) {
        int e = e0 + tid;
        if (e < E) {
            float s = rowsum[tid][0] + rowsum[tid][1] + b2[0];
            s = fmaxf(s, 0.f);
            out[e] = 1.0f / (1.0f + expf(-s));
        }
    }
}

extern "C" void kernel_launch(void* const* d_in, const int* in_sizes, int n_in,
                              void* d_out, int out_size, void* d_ws, size_t ws_size,
                              hipStream_t stream) {
    const float* x  = (const float*)d_in[0];
    const int*   ei = (const int*)d_in[1];
    const float* W1 = (const float*)d_in[2];
    const float* b1 = (const float*)d_in[3];
    const float* W2 = (const float*)d_in[4];
    const float* b2 = (const float*)d_in[5];
    float* out = (float*)d_out;

    int E = in_sizes[1] / 2;
    int N = in_sizes[0] / D;

    size_t y_bytes = (size_t)N * 256;                    // 25.6 MB fp8
    if (ws_size >= y_bytes) {
        unsigned char* Y8 = (unsigned char*)d_ws;
        int ntiles = (N + 31) / 32;
        int gridA  = (ntiles < GRIDA) ? ntiles : GRIDA;  // 3 blocks/CU, grid-stride
        precompute_kernel<<<gridA, 256, 0, stream>>>(x, W1, b1, Y8, N, ntiles);
        int gridB = (E + EPB - 1) / EPB;
        edge_kernel<<<gridB, 256, 0, stream>>>(Y8, ei, W2, b2, out, E);
    } else {
        int nblocks = (E + BM - 1) / BM;
        decoder_fallback_kernel<<<nblocks, 256, 0, stream>>>(
            x, ei, W1, b1, W2, b2, out, E);
    }
}

// Round 11
// 129.368 us; speedup vs baseline: 1.1968x; 1.0106x over previous
//
#include <hip/hip_runtime.h>
#include <hip/hip_bf16.h>
#include <hip/hip_fp16.h>
#include <math.h>

// Decoder: out[e] = sigmoid(relu( W2 . relu( W1 * [x[src]; x[dst]] + b1 ) + b2 ))
// Factorized: Y[n][0:128] = W1_left*x[n] + b1 ; Y[n][128:256] = W1_right*x[n]
//             out[e] = sigmoid(relu( W2 . relu(Yl[src]+Yr[dst]) + b2 ))
// Y stored fp8 e4m3 (25.6 MB).
// LEDGER (measured): fills+gaps 86.3 | pre: R12-struct+swENC 22.6 (R17 dup),
// barrier-free 50.7 (R18 PMC: latency-bound), counted-vmcnt ring 29.2 (R19
// algebra: REGRESSION -- raw s_barrier makes the compiler insert its own
// vmcnt(0) before the ds_reads, draining the prefetch anyway; rule #18) |
// edge: sw-decode 23.4, asm-f32-decode 15.2 (fp8 cvt builtins ABSENT on this
// toolchain; inline asm is required).
// R20 = recombination of measured-best pieces, no speculation:
//   precompute = R12 structure VERBATIM (2-buf, vmcnt(0)+__syncthreads,
//   stage-after-reads) + asm enc2 (R12's 22.6 still ran ~200 sw-encode
//   VALU/tile) + b1 hoisted to regs. Edge = R18 verbatim.
// Predict: pre ~19-21, total ~121-124us.

typedef short    s16x4 __attribute__((ext_vector_type(4)));
typedef short    s16x8 __attribute__((ext_vector_type(8)));
typedef float    f32x2 __attribute__((ext_vector_type(2)));
typedef float    f32x4 __attribute__((ext_vector_type(4)));
typedef unsigned u32x4 __attribute__((ext_vector_type(4)));
typedef _Float16 h16x2 __attribute__((ext_vector_type(2)));

#define D 128

static __device__ inline short f2bf(float f) {
    unsigned u = __builtin_bit_cast(unsigned, f);
    unsigned r = (u + 0x7FFFu + ((u >> 16) & 1u)) >> 16;
    return (short)r;
}

// f32 pair -> packed bf16 dword (RNE), gfx950
static __device__ inline unsigned pkbf16(float a, float b) {
    unsigned r;
    asm("v_cvt_pk_bf16_f32 %0, %1, %2" : "=v"(r) : "v"(a), "v"(b));
    return r;
}

// async global->LDS 16B; LDS dest = wave-uniform base + lane*16 (m104)
static __device__ inline void stage16(const void* g, void* l) {
    __builtin_amdgcn_global_load_lds(
        (const __attribute__((address_space(1))) void*)g,
        (__attribute__((address_space(3))) void*)l, 16, 0, 0);
}

// ---------- fp8 e4m3 encode: builtin or direct asm (builtins absent here) ----------
static __device__ inline unsigned enc2(float a, float b) {
#if __has_builtin(__builtin_amdgcn_cvt_pk_fp8_f32)
    return ((unsigned)__builtin_amdgcn_cvt_pk_fp8_f32(a, b, 0, false)) & 0xFFFFu;
#else
    unsigned r;
    asm("v_cvt_pk_fp8_f32 %0, %1, %2" : "=v"(r) : "v"(a), "v"(b));
    return r & 0xFFFFu;
#endif
}

// ---------- fp8 e4m3 decode: f16-pk builtin > f32-pk builtin > f32-pk asm ----------
#if __has_builtin(__builtin_amdgcn_cvt_pk_f16_fp8)
#define EDGE_PATH 0
#define YSC 1.0f
static __device__ inline h16x2 dec2lo(unsigned v) {
    return __builtin_amdgcn_cvt_pk_f16_fp8((short)v);
}
static __device__ inline h16x2 dec2hi(unsigned v) {
    return __builtin_amdgcn_cvt_pk_f16_fp8((short)(v >> 16));
}
static __device__ inline h16x2 reluh(h16x2 v) {
#if __has_builtin(__builtin_elementwise_max)
    h16x2 z = { (_Float16)0.0f, (_Float16)0.0f };
    return __builtin_elementwise_max(v, z);
#else
    unsigned u = __builtin_bit_cast(unsigned, v);
    unsigned m = ((u >> 15) & 0x00010001u) * 0xFFFFu;
    u &= ~m;
    return __builtin_bit_cast(h16x2, u);
#endif
}
static __device__ inline float dot2acc(h16x2 a, h16x2 b, float c) {
#if __has_builtin(__builtin_amdgcn_fdot2)
    return __builtin_amdgcn_fdot2(a, b, c, false);
#else
    return c + (float)a[0] * (float)b[0] + (float)a[1] * (float)b[1];
#endif
}
#else
#define EDGE_PATH 1
#if __has_builtin(__builtin_amdgcn_cvt_pk_f32_fp8)
static __device__ inline f32x2 d32lo(unsigned v) {
    return __builtin_amdgcn_cvt_pk_f32_fp8((int)v, false);
}
static __device__ inline f32x2 d32hi(unsigned v) {
    return __builtin_amdgcn_cvt_pk_f32_fp8((int)v, true);
}
#else
static __device__ inline f32x2 d32lo(unsigned v) {
    f32x2 r;
    asm("v_cvt_pk_f32_fp8 %0, %1" : "=v"(r) : "v"(v));
    return r;
}
static __device__ inline f32x2 d32hi(unsigned v) {
    f32x2 r;
    unsigned s = v >> 16;
    asm("v_cvt_pk_f32_fp8 %0, %1" : "=v"(r) : "v"(s));
    return r;
}
#endif
#endif

// ---------------- Phase A: Y^T MFMA, gload_lds staging (R12 structure) ----------------
#define GRIDA 768   // 3 blocks/CU x 256 CUs

__global__ __launch_bounds__(256, 3) void precompute_kernel(
    const float* __restrict__ x,    // [N,128]
    const float* __restrict__ W1,   // [128,256]
    const float* __restrict__ b1,   // [128]
    unsigned char* __restrict__ Y8, // [N,256] fp8 e4m3
    int N, int ntiles)
{
    // 2 x 32 rows x 512B, rows XOR-swizzled by ((row&7)<<4) on both sides
    __shared__ float Xt[2][32 * 128];

    const int tid  = threadIdx.x;
    const int wid  = tid >> 6;                   // wave id = 64-feature col slice
    const int lane = tid & 63;
    const int quad = lane >> 4, l15 = lane & 15;
    const int cs   = wid;

    // ---- W1 bf16 A-frags (prologue, once per block; asm cvt)
    // frag (c,j): lane -> W1row[o=cs*64+j*16+l15][k=c*32+quad*8 .. +8]
    s16x8 bf[4][4];   // [k-chunk][col-tile]
    #pragma unroll
    for (int j = 0; j < 4; ++j) {
        #pragma unroll
        for (int c = 0; c < 4; ++c) {
            int o  = cs * 64 + j * 16 + l15;
            int kb = c * 32 + quad * 8;
            const float* wp = W1 + (size_t)(o & 127) * 256 + (o >> 7) * 128 + kb;
            f32x4 u0 = *(const f32x4*)wp;
            f32x4 u1 = *(const f32x4*)(wp + 4);
            u32x4 pk;
            pk[0] = pkbf16(u0[0], u0[1]);
            pk[1] = pkbf16(u0[2], u0[3]);
            pk[2] = pkbf16(u1[0], u1[1]);
            pk[3] = pkbf16(u1[2], u1[3]);
            bf[c][j] = __builtin_bit_cast(s16x8, pk);
        }
    }

    // ---- b1 hoisted to regs (left-half col slices only)
    f32x4 b1v[4];
    #pragma unroll
    for (int j = 0; j < 4; ++j)
        b1v[j] = (cs < 2) ? *(const f32x4*)&b1[cs * 64 + j * 16 + quad * 4]
                          : (f32x4){0.f, 0.f, 0.f, 0.f};

    // staging geometry: thread covers LDS bytes i*4096 + tid*16, i=0..3
    const int rl   = wid * 2 + (lane >> 5);      // row = i*8 + rl
    const int colb = (lane & 31) * 16;           // in-row byte offset (pre-swizzle)
    const char* xbytes = (const char*)x;

    auto stage_tile = [&](int tt, int bb) {
        char* lb = (char*)&Xt[bb][0] + wid * 1024;   // wave-uniform base
        #pragma unroll
        for (int i = 0; i < 4; ++i) {
            int row = i * 8 + rl;
            int m = tt * 32 + row; if (m >= N) m = N - 1;
            // LDS holds X[row][col ^ sw(row)] at linear (row,col): pre-swizzle src
            stage16(xbytes + (size_t)m * 512 + (colb ^ ((row & 7) << 4)),
                    lb + i * 4096);
        }
    };

    int t = blockIdx.x;
    if (t < ntiles) stage_tile(t, 0);

    const int swz = (l15 & 7) << 4;              // read-side swizzle
    const bool qb0 = (quad & 1), qb1 = (quad & 2);
    int buf = 0;
    while (t < ntiles) {
        const int tn = t + GRIDA;

        // ---- drain own staging, then barrier (compiler models the drain)
        asm volatile("s_waitcnt vmcnt(0)" ::: "memory");
        __syncthreads();

        // ---- acc init = bias (from regs)
        f32x4 acc[2][4];
        #pragma unroll
        for (int j = 0; j < 4; ++j) { acc[0][j] = b1v[j]; acc[1][j] = b1v[j]; }

        // ---- read x frags from swizzled LDS, convert f32->bf16 in-reg
        s16x8 af[2][4];   // [i2][c]
        {
            const char* xb8 = (const char*)&Xt[buf][0];
            #pragma unroll
            for (int i2 = 0; i2 < 2; ++i2) {
                const char* rp = xb8 + (i2 * 16 + l15) * 512;
                #pragma unroll
                for (int c = 0; c < 4; ++c) {
                    int kb = c * 128 + quad * 32;
                    f32x4 lo = *(const f32x4*)(rp + ( kb       ^ swz));
                    f32x4 hi = *(const f32x4*)(rp + ((kb + 16) ^ swz));
                    u32x4 pk;
                    pk[0] = pkbf16(lo[0], lo[1]);
                    pk[1] = pkbf16(lo[2], lo[3]);
                    pk[2] = pkbf16(hi[0], hi[1]);
                    pk[3] = pkbf16(hi[2], hi[3]);
                    af[i2][c] = __builtin_bit_cast(s16x8, pk);
                }
            }
        }

        // ---- issue next tile's staging (lands during MFMA + epilogue;
        //      drained at next iteration's vmcnt(0)+barrier)
        if (tn < ntiles) stage_tile(tn, buf ^ 1);

        // ---- MFMA: D = W1frag x xfrag = Y^T (row=feature, col=node)
        #pragma unroll
        for (int c = 0; c < 4; ++c)
            #pragma unroll
            for (int i2 = 0; i2 < 2; ++i2)
                #pragma unroll
                for (int j = 0; j < 4; ++j)
                    acc[i2][j] = __builtin_amdgcn_mfma_f32_16x16x32_bf16(
                        bf[c][j], af[i2][c], acc[i2][j], 0, 0, 0);

        // ---- epilogue: asm fp8 encode + 4x4 quad transpose -> 16B stores
        // D layout: col=l15 -> node (m0+i2*16+l15), row=quad*4+r -> feature
        const int m0 = t * 32;
        #pragma unroll
        for (int i2 = 0; i2 < 2; ++i2) {
            unsigned dw[4];
            #pragma unroll
            for (int j = 0; j < 4; ++j) {
                f32x4 v = acc[i2][j];
                dw[j] = enc2(v[0], v[1]) | (enc2(v[2], v[3]) << 16);
            }
            // transpose across quads: lane q ends with {dw[q] of quad 0..3}
            // = 16 consecutive features at col cs*64+q*16
            unsigned s01 = qb0 ? dw[0] : dw[1];
            unsigned r01 = __shfl_xor(s01, 16);
            unsigned s23 = qb0 ? dw[2] : dw[3];
            unsigned r23 = __shfl_xor(s23, 16);
            unsigned a0 = qb0 ? r01 : dw[0];
            unsigned a1 = qb0 ? dw[1] : r01;
            unsigned a2 = qb0 ? r23 : dw[2];
            unsigned a3 = qb0 ? dw[3] : r23;
            unsigned s02 = qb1 ? a0 : a2;
            unsigned r02 = __shfl_xor(s02, 32);
            unsigned s13 = qb1 ? a1 : a3;
            unsigned r13 = __shfl_xor(s13, 32);
            uint4 ov;
            ov.x = qb1 ? r02 : a0;
            ov.y = qb1 ? r13 : a1;
            ov.z = qb1 ? a2 : r02;
            ov.w = qb1 ? a3 : r13;
            int m = m0 + i2 * 16 + l15;
            if (m < N)
                *(uint4*)(Y8 + (size_t)m * 256 + cs * 64 + quad * 16) = ov;
        }

        buf ^= 1;
        t = tn;
    }
}

// ---------------- Phase B: 8 edges per 8-lane group, fp8 gather (R18) ----------------
#define EPB 256   // edges per block (256 threads, 32 groups x 8 edges)

__global__ __launch_bounds__(256, 4) void edge_kernel(
    const unsigned char* __restrict__ Y8,  // [N,256] fp8
    const int*           __restrict__ ei,  // [2,E]
    const float*         __restrict__ W2,  // [128]
    const float*         __restrict__ b2,  // [1]
    float*               __restrict__ out, // [E]
    int E)
{
    __shared__ int eis[2][EPB];                 // [src/dst][edge-in-block]

    const int tid = threadIdx.x;
    const int sub = tid & 7;                    // 8 lanes per edge
    const int grp = tid >> 3;                   // 0..31
    const int e0b = blockIdx.x * EPB;

    {
        int e = e0b + tid;
        eis[0][tid] = (e < E) ? ei[e] : 0;
        eis[1][tid] = (e < E) ? ei[(size_t)E + e] : 0;
    }
    __syncthreads();

#if EDGE_PATH == 1
    f32x2 w2f[8];
    {
        const float* wp = &W2[sub * 16];
        #pragma unroll
        for (int q = 0; q < 8; ++q)
            w2f[q] = *(const f32x2*)(wp + q * 2);
    }
#else
    h16x2 w2h[8];
    {
        const float* wp = &W2[sub * 16];
        #pragma unroll
        for (int q = 0; q < 8; ++q) {
            float2 f = *(const float2*)(wp + q * 2);
            w2h[q] = (h16x2){ (_Float16)(f.x * YSC), (_Float16)(f.y * YSC) };
        }
    }
#endif

    uint4 L[8], R[8];
    #pragma unroll
    for (int k = 0; k < 8; ++k) {
        int ib  = grp + 32 * k;
        int src = eis[0][ib];
        int dst = eis[1][ib];
        L[k] = *(const uint4*)(Y8 + (size_t)src * 256 + sub * 16);
        R[k] = *(const uint4*)(Y8 + (size_t)dst * 256 + 128 + sub * 16);
    }

    float s[8] = { 0.f, 0.f, 0.f, 0.f, 0.f, 0.f, 0.f, 0.f };
    #pragma unroll
    for (int k = 0; k < 8; ++k) {
        const unsigned* a = (const unsigned*)&L[k];
        const unsigned* c = (const unsigned*)&R[k];
        #pragma unroll
        for (int d = 0; d < 4; ++d) {
#if EDGE_PATH == 1
            f32x2 zl = d32lo(a[d]) + d32lo(c[d]);
            f32x2 zh = d32hi(a[d]) + d32hi(c[d]);
            s[k] = fmaf(fmaxf(zl[0], 0.f), w2f[2*d][0], s[k]);
            s[k] = fmaf(fmaxf(zl[1], 0.f), w2f[2*d][1], s[k]);
            s[k] = fmaf(fmaxf(zh[0], 0.f), w2f[2*d + 1][0], s[k]);
            s[k] = fmaf(fmaxf(zh[1], 0.f), w2f[2*d + 1][1], s[k]);
#else
            h16x2 za = reluh(dec2lo(a[d]) + dec2lo(c[d]));
            s[k] = dot2acc(za, w2h[2*d],     s[k]);
            h16x2 zb = reluh(dec2hi(a[d]) + dec2hi(c[d]));
            s[k] = dot2acc(zb, w2h[2*d + 1], s[k]);
#endif
        }
    }

    #pragma unroll
    for (int k = 0; k < 8; ++k) {
        s[k] += __shfl_xor(s[k], 1);
        s[k] += __shfl_xor(s[k], 2);
        s[k] += __shfl_xor(s[k], 4);
    }

    if (sub == 0) {
        float bb = b2[0];
        #pragma unroll
        for (int k = 0; k < 8; ++k) {
            int e = e0b + grp + 32 * k;
            if (e < E) {
                float t = fmaxf(s[k] + bb, 0.f);
                out[e] = 1.0f / (1.0f + expf(-t));
            }
        }
    }
}

// ---------------- fallback (fused edge-wise GEMM, fp32 inputs) ----------------
#define BM   128
#define BK   64
#define LDT  72

__global__ __launch_bounds__(256) void decoder_fallback_kernel(
    const float* __restrict__ x, const int* __restrict__ ei,
    const float* __restrict__ W1, const float* __restrict__ b1,
    const float* __restrict__ W2, const float* __restrict__ b2,
    float* __restrict__ out, int E)
{
    __shared__ int   nid[2][BM];
    __shared__ short At[BM * LDT];
    __shared__ short Bt[D * LDT];
    __shared__ float rowsum[BM][2];

    const int tid = threadIdx.x;
    const int e0  = blockIdx.x * BM;
    if (tid < BM) { int e = e0 + tid; nid[0][tid] = (e < E) ? ei[e] : 0; }
    else { int e = e0 + (tid - BM); nid[1][tid - BM] = (e < E) ? ei[E + e] : 0; }

    const int wid = tid >> 6, lane = tid & 63;
    const int wm = wid >> 1, wn = wid & 1;
    const int quad = lane >> 4, l15 = lane & 15;
    const int srow = tid >> 4, scol = (tid & 15) * 4;
    f32x4 acc[4][4] = {};
    __syncthreads();

    for (int t = 0; t < 4; ++t) {
        const int* ids = nid[t >> 1];
        const int kx = (t & 1) * BK, kw = t * BK;
        #pragma unroll
        for (int p = 0; p < 8; ++p) {
            int row = srow + p * 16;
            float4 v = *(const float4*)&x[(size_t)ids[row] * D + kx + scol];
            s16x4 bv = { f2bf(v.x), f2bf(v.y), f2bf(v.z), f2bf(v.w) };
            *(s16x4*)&At[row * LDT + scol] = bv;
        }
        #pragma unroll
        for (int p = 0; p < 8; ++p) {
            int n = srow + p * 16;
            float4 v = *(const float4*)&W1[n * 256 + kw + scol];
            s16x4 bv = { f2bf(v.x), f2bf(v.y), f2bf(v.z), f2bf(v.w) };
            *(s16x4*)&Bt[n * LDT + scol] = bv;
        }
        __syncthreads();
        #pragma unroll
        for (int c = 0; c < 2; ++c) {
            const int kc = c * 32;
            s16x8 af[4], bfr[4];
            #pragma unroll
            for (int i = 0; i < 4; ++i)
                af[i] = *(const s16x8*)&At[(wm*64 + i*16 + l15) * LDT + kc + quad*8];
            #pragma unroll
            for (int j = 0; j < 4; ++j)
                bfr[j] = *(const s16x8*)&Bt[(wn*64 + j*16 + l15) * LDT + kc + quad*8];
            #pragma unroll
            for (int i = 0; i < 4; ++i)
                #pragma unroll
                for (int j = 0; j < 4; ++j)
                    acc[i][j] = __builtin_amdgcn_mfma_f32_16x16x32_bf16(
                        af[i], bfr[j], acc[i][j], 0, 0, 0);
        }
        __syncthreads();
    }
    float b1v[4], w2v[4];
    #pragma unroll
    for (int j = 0; j < 4; ++j) {
        int col = wn*64 + j*16 + l15;
        b1v[j] = b1[col]; w2v[j] = W2[col];
    }
    float psum[16];
    #pragma unroll
    for (int t = 0; t < 16; ++t) psum[t] = 0.f;
    #pragma unroll
    for (int i = 0; i < 4; ++i)
        #pragma unroll
        for (int j = 0; j < 4; ++j)
            #pragma unroll
            for (int r = 0; r < 4; ++r) {
                float c = fmaxf(acc[i][j][r] + b1v[j], 0.f);
                psum[i*4 + r] += c * w2v[j];
            }
    #pragma unroll
    for (int off = 1; off < 16; off <<= 1)
        #pragma unroll
        for (int t = 0; t < 16; ++t)
            psum[t] += __shfl_xor(psum[t], off);
    if (l15 == 0) {
        #pragma unroll
        for (int i = 0; i < 4; ++i)
            #pragma unroll
            for (int r = 0; r < 4; ++r)
                rowsum[wm*64 + i*16 + quad*4 + r][wn] = psum[i*4 + r];
    }
    __syncthreads();
    if (tid < BM) {
        int e = e0 + tid;
        if (e < E) {
            float s = rowsum[tid][0] + rowsum[tid][1] + b2[0];
            s = fmaxf(s, 0.f);
            out[e] = 1.0f / (1.0f + expf(-s));
        }
    }
}

extern "C" void kernel_launch(void* const* d_in, const int* in_sizes, int n_in,
                              void* d_out, int out_size, void* d_ws, size_t ws_size,
                              hipStream_t stream) {
    const float* x  = (const float*)d_in[0];
    const int*   ei = (const int*)d_in[1];
    const float* W1 = (const float*)d_in[2];
    const float* b1 = (const float*)d_in[3];
    const float* W2 = (const float*)d_in[4];
    const float* b2 = (const float*)d_in[5];
    float* out = (float*)d_out;

    int E = in_sizes[1] / 2;
    int N = in_sizes[0] / D;

    size_t y_bytes = (size_t)N * 256;                    // 25.6 MB fp8
    if (ws_size >= y_bytes) {
        unsigned char* Y8 = (unsigned char*)d_ws;
        int ntiles = (N + 31) / 32;
        int gridA  = (ntiles < GRIDA) ? ntiles : GRIDA;  // 3 blocks/CU, grid-stride
        precompute_kernel<<<gridA, 256, 0, stream>>>(x, W1, b1, Y8, N, ntiles);
        int gridB = (E + EPB - 1) / EPB;
        edge_kernel<<<gridB, 256, 0, stream>>>(Y8, ei, W2, b2, out, E);
    } else {
        int nblocks = (E + BM - 1) / BM;
        decoder_fallback_kernel<<<nblocks, 256, 0, stream>>>(
            x, ei, W1, b1, W2, b2, out, E);
    }
}